// Round 21
// baseline (99.293 us; speedup 1.0000x reference)
//
#include <hip/hip_runtime.h>
#include <math.h>

#define LOG2E_F 1.4426950408889634f
#define LN2_F   0.6931471805599453f

constexpr int Bn = 1024;
constexpr int Tn = 512;
constexpr int Ln = 32;

typedef unsigned int uint2v __attribute__((ext_vector_type(2)));
typedef float f32x4v __attribute__((ext_vector_type(4)));

// ---- cross-lane swaps (runtime-probed mapping, VALU permlane ops) ----------
#if __has_builtin(__builtin_amdgcn_permlane32_swap)
#define PROBE32 \
    bool use_y32; \
    { \
        const uint2v r = __builtin_amdgcn_permlane32_swap((unsigned)l, (unsigned)l, false, false); \
        const bool selA = __all((((l < 32) ? (int)r[1] : (int)r[0]) == (l ^ 32)) ? 1 : 0); \
        use_y32 = selA ? (l < 32) : (l >= 32); \
    }
#define CROSS32(p, out) { \
    const uint2v r_ = __builtin_amdgcn_permlane32_swap( \
        __float_as_uint(p), __float_as_uint(p), false, false); \
    out = __uint_as_float(use_y32 ? r_[1] : r_[0]); }
#else
#define PROBE32
#define CROSS32(p, out) out = __shfl_xor((p), 32);
#endif

#if __has_builtin(__builtin_amdgcn_permlane16_swap)
#define PROBE16 \
    bool use_r016; \
    { \
        const uint2v r = __builtin_amdgcn_permlane16_swap((unsigned)l, (unsigned)l, false, false); \
        const bool selA = __all(((((l & 16) ? (int)r[0] : (int)r[1])) == (l ^ 16)) ? 1 : 0); \
        use_r016 = selA ? ((l & 16) != 0) : ((l & 16) == 0); \
    }
#define CROSS16(p, out) { \
    const uint2v r_ = __builtin_amdgcn_permlane16_swap( \
        __float_as_uint(p), __float_as_uint(p), false, false); \
    out = __uint_as_float(use_r016 ? r_[0] : r_[1]); }
#else
#define PROBE16
#define CROSS16(p, out) out = __int_as_float(__builtin_amdgcn_ds_swizzle( \
        __float_as_int(p), 0x401F));
#endif

// ---- emission loads: round-13/16-PROVEN form (voff VGPR, uniform s-base) ---
#define ISS1(REG, TT, COL) {                                                \
    int ts_ = (TT);                                                         \
    ts_ = ts_ < 0 ? 0 : (ts_ > (Tn - 1) ? (Tn - 1) : ts_);                  \
    const unsigned voff_ = (unsigned)ts_ * (unsigned)(Ln * 4) + (COL);      \
    asm volatile("global_load_dword %0, %1, %2"                             \
                 : "=v"(REG) : "v"(voff_), "s"(xb)); }

#define ISSUE16(P, TB)                                                      \
    ISS1(P##0,  (TB),            col4O) ISS1(P##1,  (TB) + 1  * dtt, col4E) \
    ISS1(P##2,  (TB) + 2 * dtt,  col4O) ISS1(P##3,  (TB) + 3  * dtt, col4E) \
    ISS1(P##4,  (TB) + 4 * dtt,  col4O) ISS1(P##5,  (TB) + 5  * dtt, col4E) \
    ISS1(P##6,  (TB) + 6 * dtt,  col4O) ISS1(P##7,  (TB) + 7  * dtt, col4E) \
    ISS1(P##8,  (TB) + 8 * dtt,  col4O) ISS1(P##9,  (TB) + 9  * dtt, col4E) \
    ISS1(P##10, (TB) + 10 * dtt, col4O) ISS1(P##11, (TB) + 11 * dtt, col4E) \
    ISS1(P##12, (TB) + 12 * dtt, col4O) ISS1(P##13, (TB) + 13 * dtt, col4E) \
    ISS1(P##14, (TB) + 14 * dtt, col4O) ISS1(P##15, (TB) + 15 * dtt, col4E)

#define WAITALL(P)                                                          \
    asm volatile("s_waitcnt vmcnt(0)"                                       \
        : "+v"(P##0), "+v"(P##1), "+v"(P##2),  "+v"(P##3),                  \
          "+v"(P##4), "+v"(P##5), "+v"(P##6),  "+v"(P##7),                  \
          "+v"(P##8), "+v"(P##9), "+v"(P##10), "+v"(P##11),                 \
          "+v"(P##12), "+v"(P##13), "+v"(P##14), "+v"(P##15)                \
        : : "memory");

#define COPY16(D, S)                                                        \
    D##0 = S##0;   D##1 = S##1;   D##2 = S##2;   D##3 = S##3;               \
    D##4 = S##4;   D##5 = S##5;   D##6 = S##6;   D##7 = S##7;               \
    D##8 = S##8;   D##9 = S##9;   D##10 = S##10; D##11 = S##11;             \
    D##12 = S##12; D##13 = S##13; D##14 = S##14; D##15 = S##15;

// ---- fused rotate-multiply: VOP2 DPP (one instruction per term) ------------
#define MULDPP(ACC, XS, EV, T)                                              \
    asm("v_mul_f32_dpp %0, %1, %2 row_ror:" #T " row_mask:0xf bank_mask:0xf"\
        : "=v"(ACC) : "v"(XS), "v"(EV));
#define FMACDPP(ACC, XS, EV, T)                                             \
    asm("v_fmac_f32_dpp %0, %1, %2 row_ror:" #T " row_mask:0xf bank_mask:0xf"\
        : "+v"(ACC) : "v"(XS), "v"(EV));

// ---- step core: alternating layout, ONE cross per step, DIR compile-time --
#define STEP_BODY(ET, CRX, PRE, NXTV)                                       \
    const float gcur = ggc;                                                 \
    if (PRE) ggc = __builtin_amdgcn_exp2f((NXTV) * LOG2E_F);                \
    float xs;                                                               \
    if constexpr (DIR) {                                                    \
        asm("v_mul_f32 %0, %1, %2\n\ts_nop 1"                               \
            : "=v"(xs) : "v"(x), "v"(gcur));                                \
    } else {                                                                \
        asm("v_mov_b32 %0, %1\n\ts_nop 1" : "=v"(xs) : "v"(x));             \
    }                                                                       \
    float a0, a1, a2, a3;                                                   \
    a0 = xs * ET[0];                                                        \
    MULDPP(a1, xs, ET[1], 1)                                                \
    MULDPP(a2, xs, ET[2], 2)                                                \
    MULDPP(a3, xs, ET[3], 3)                                                \
    FMACDPP(a0, xs, ET[4],  4)                                              \
    FMACDPP(a1, xs, ET[5],  5)                                              \
    FMACDPP(a2, xs, ET[6],  6)                                              \
    FMACDPP(a3, xs, ET[7],  7)                                              \
    FMACDPP(a0, xs, ET[8],  8)                                              \
    FMACDPP(a1, xs, ET[9],  9)                                              \
    FMACDPP(a2, xs, ET[10], 10)                                             \
    FMACDPP(a3, xs, ET[11], 11)                                             \
    FMACDPP(a0, xs, ET[12], 12)                                             \
    FMACDPP(a1, xs, ET[13], 13)                                             \
    FMACDPP(a2, xs, ET[14], 14)                                             \
    FMACDPP(a3, xs, ET[15], 15)                                             \
    const float partial = (a0 + a1) + (a2 + a3);                            \
    float cross; CRX(partial, cross)                                        \
    float full = partial + cross;                                           \
    if constexpr (!DIR) full *= gcur;      /* fw: emission at reader */

#define RENORM {                                                            \
    const int cb = __builtin_amdgcn_readfirstlane(                          \
        __float_as_int(fmaxf(capv, 1e-30f)));                               \
    const int ee = ((cb >> 23) & 255) - 127;                                \
    x *= __int_as_float((127 - ee) << 23);                                  \
    Mr += (float)ee; }

#define STEPF(ET, CRX, PRE, NXTV, CAP, RN) {                                \
    STEP_BODY(ET, CRX, PRE, NXTV)                                           \
    x = full;                                                               \
    if (CAP) capv = x;                                                      \
    if (RN) RENORM }

#define STEPT(R, ET, CRX, PRE, NXTV, CAP, RN) {                             \
    STEP_BODY(ET, CRX, PRE, NXTV)                                           \
    const bool act = ((kb + (R)) <= K);                                     \
    x = act ? full : x;                                                     \
    if (CAP) capv = x;                                                      \
    if (RN) RENORM }

#define STEPS16F(P)                                                         \
    ggc = __builtin_amdgcn_exp2f(P##0 * LOG2E_F);                           \
    STEPF(EiA, CROSS16, 1, P##1,  0, 0)                                     \
    STEPF(EiB, CROSS32, 1, P##2,  0, 0)                                     \
    STEPF(EiA, CROSS16, 1, P##3,  1, 0)                                     \
    STEPF(EiB, CROSS32, 1, P##4,  0, 1)                                     \
    STEPF(EiA, CROSS16, 1, P##5,  0, 0)                                     \
    STEPF(EiB, CROSS32, 1, P##6,  0, 0)                                     \
    STEPF(EiA, CROSS16, 1, P##7,  1, 0)                                     \
    STEPF(EiB, CROSS32, 1, P##8,  0, 1)                                     \
    STEPF(EiA, CROSS16, 1, P##9,  0, 0)                                     \
    STEPF(EiB, CROSS32, 1, P##10, 0, 0)                                     \
    STEPF(EiA, CROSS16, 1, P##11, 1, 0)                                     \
    STEPF(EiB, CROSS32, 1, P##12, 0, 1)                                     \
    STEPF(EiA, CROSS16, 1, P##13, 0, 0)                                     \
    STEPF(EiB, CROSS32, 1, P##14, 0, 0)                                     \
    STEPF(EiA, CROSS16, 1, P##15, 1, 0)                                     \
    STEPF(EiB, CROSS32, 0, P##15, 0, 1)                                     \
    kb += 16;

#define STEPS16T(P)                                                         \
    ggc = __builtin_amdgcn_exp2f(P##0 * LOG2E_F);                           \
    STEPT(0,  EiA, CROSS16, 1, P##1,  0, 0)                                 \
    STEPT(1,  EiB, CROSS32, 1, P##2,  0, 0)                                 \
    STEPT(2,  EiA, CROSS16, 1, P##3,  1, 0)                                 \
    STEPT(3,  EiB, CROSS32, 1, P##4,  0, 1)                                 \
    STEPT(4,  EiA, CROSS16, 1, P##5,  0, 0)                                 \
    STEPT(5,  EiB, CROSS32, 1, P##6,  0, 0)                                 \
    STEPT(6,  EiA, CROSS16, 1, P##7,  1, 0)                                 \
    STEPT(7,  EiB, CROSS32, 1, P##8,  0, 1)                                 \
    STEPT(8,  EiA, CROSS16, 1, P##9,  0, 0)                                 \
    STEPT(9,  EiB, CROSS32, 1, P##10, 0, 0)                                 \
    STEPT(10, EiA, CROSS16, 1, P##11, 1, 0)                                 \
    STEPT(11, EiB, CROSS32, 1, P##12, 0, 1)                                 \
    STEPT(12, EiA, CROSS16, 1, P##13, 0, 0)                                 \
    STEPT(13, EiB, CROSS32, 1, P##14, 0, 0)                                 \
    STEPT(14, EiA, CROSS16, 1, P##15, 1, 0)                                 \
    STEPT(15, EiB, CROSS32, 0, P##15, 0, 1)                                 \
    kb += 16;

#define EI_SETUP2                                                           \
    float EiA[16], EiB[16];                                                 \
    {                                                                       \
        float tmax = -3.4e38f;                                              \
        _Pragma("unroll")                                                   \
        for (int t = 0; t < 16; ++t) {                                      \
            const int sg = ror_minus ? ((k15 - t) & 15) : ((k15 + t) & 15); \
            const int iA = 16 * ihA + sg;                                   \
            const int iB = 16 * ihB + sg;                                   \
            const float tvA = DIR ? trans[labA * Ln + iA]                   \
                                  : trans[iA * Ln + labA];                  \
            const float tvB = DIR ? trans[labB * Ln + iB]                   \
                                  : trans[iB * Ln + labB];                  \
            EiA[t] = tvA;  EiB[t] = tvB;                                    \
            tmax = fmaxf(tmax, tvA);    /* EA spans all of trans */         \
        }                                                                   \
        _Pragma("unroll")                                                   \
        for (int off = 1; off < 64; off <<= 1)                              \
            tmax = fmaxf(tmax, __shfl_xor(tmax, off));                      \
        tmax2 = tmax * LOG2E_F;                                             \
        _Pragma("unroll")                                                   \
        for (int t = 0; t < 16; ++t) {                                      \
            EiA[t] = __builtin_amdgcn_exp2f((EiA[t] - tmax) * LOG2E_F);     \
            EiB[t] = __builtin_amdgcn_exp2f((EiB[t] - tmax) * LOG2E_F);     \
        }                                                                   \
    }

// ---- chain body, DIR compile-time (round-16 verbatim, known-good) ----------
template<int DIR>
__device__ __forceinline__ void chain_run(const float* __restrict__ logits,
                                          const float* __restrict__ trans,
                                          const int b, const int l,
                                          const int len,
                                          float* __restrict__ ws)
{
    const int k15 = l & 15;
    const int labB = l & 31;                        // phi label
    const int labA = (l & 15) | ((l >> 5) << 4);    // sigma label
    const int ihA  = (l >> 4) & 1;                  // row-half, phi-layout
    const int ihB  = (l >> 5) & 1;                  // row-half, sigma-layout

    const int m  = (len + 1) >> 1;
    const int K  = DIR ? (len - m) : (m - 1);
    const int nfull = K >> 4;
    const int ktail = K & 15;

    const float* xb = logits + (size_t)b * (Tn * Ln);

    const int w0 = __builtin_amdgcn_readfirstlane(
        __builtin_amdgcn_update_dpp(0, l, 0x121, 0xF, 0xF, true));
    const bool ror_minus = (w0 == 15);
    PROBE32
    PROBE16

    float tmax2;
    EI_SETUP2

    // init state in phi-layout
    float x, Minit;
    if constexpr (DIR == 0) {
        const float a0v = xb[labB] * LOG2E_F;
        float mx = a0v;
        #pragma unroll
        for (int off = 1; off < 64; off <<= 1)
            mx = fmaxf(mx, __shfl_xor(mx, off));
        x = __builtin_amdgcn_exp2f(a0v - mx);
        Minit = mx;
    } else {
        x = 1.0f;
        Minit = 0.0f;
    }
    float Mr = 0.0f;
    float capv = x;

    const unsigned col4O = (unsigned)(DIR ? labB : labA) * 4u;
    const unsigned col4E = (unsigned)(DIR ? labA : labB) * 4u;
    const int dtt = DIR ? -1 : 1;
    const int t0  = DIR ? (len - 1) : 1;

    float A0, A1, A2, A3, A4, A5, A6, A7;
    float A8, A9, A10, A11, A12, A13, A14, A15;
    float B0, B1, B2, B3, B4, B5, B6, B7;
    float B8, B9, B10, B11, B12, B13, B14, B15;

    float ggc = 1.0f;
    int kb = 1;

    ISSUE16(B, t0)
    WAITALL(B)
    COPY16(A, B)
    int tnext = t0 + 16 * dtt;

    for (int g = 0; g < nfull; ++g) {
        ISSUE16(B, tnext)
        tnext += 16 * dtt;
        __builtin_amdgcn_sched_barrier(0);
        STEPS16F(A)
        __builtin_amdgcn_sched_barrier(0);
        WAITALL(B)
        __builtin_amdgcn_sched_barrier(0);
        COPY16(A, B)
    }
    if (ktail) {
        STEPS16T(A)
    }

    asm volatile("s_waitcnt vmcnt(0)" ::: "memory");

    const float M = Minit + (float)K * tmax2 + Mr;

    // final layout depends on parity of K: even -> phi, odd -> sigma
    float* wsrow = ws + (size_t)(b * 2 + DIR) * 33;
    if (K & 1) {
        if ((l & 16) == 0) wsrow[labA] = x;
    } else {
        if (l < 32) wsrow[l] = x;
    }
    if (l == 0) wsrow[32] = M;
}

__global__ __launch_bounds__(64)
void crf_chain_kernel(const float* __restrict__ logits,
                      const float* __restrict__ trans,
                      const int* __restrict__ seq_lens,
                      float* __restrict__ ws)
{
    const int blk = blockIdx.x;
    const int b   = blk >> 1;
    const int dir = blk & 1;
    const int l   = threadIdx.x;

    int len = seq_lens[b];
    len = len < 1 ? 1 : (len > Tn ? Tn : len);
    len = __builtin_amdgcn_readfirstlane(len);   // uniform: scalar t-arithmetic

    if (dir == 0) chain_run<0>(logits, trans, b, l, len, ws);
    else          chain_run<1>(logits, trans, b, l, len, ws);
}

// ---- all-asm LDS-staging probe (output-inert; ws overwritten by chain) -----
// Every memory op is asm volatile => mutually program-ordered. Measures the
// staged-emission pipeline's speed with the production step core.
template<int NSTEP>
__global__ __launch_bounds__(64)
void crf_probe_stage(const float* __restrict__ logits,
                     const float* __restrict__ trans,
                     float* __restrict__ ws)
{
    constexpr int DIR = 0;
    __shared__ __align__(16) float plds[2][16][32];

    const int blk = blockIdx.x;
    const int b   = blk >> 1;
    const int l   = threadIdx.x;
    const int k15 = l & 15;
    const int labB = l & 31;
    const int labA = (l & 15) | ((l >> 5) << 4);
    const int ihA  = (l >> 4) & 1;
    const int ihB  = (l >> 5) & 1;

    const float* xb = logits + (size_t)b * (Tn * Ln);

    const int w0 = __builtin_amdgcn_readfirstlane(
        __builtin_amdgcn_update_dpp(0, l, 0x121, 0xF, 0xF, true));
    const bool ror_minus = (w0 == 15);
    PROBE32
    PROBE16

    float tmax2;
    EI_SETUP2
    (void)tmax2;

    float x = 1.0f + (float)labB * 0.015625f;
    float Mr = 0.0f;
    float capv = x;
    float ggc = 1.0f;
    int kb = 1;

    const unsigned aO = (unsigned)labA * 4u;   // DIR=0: odd-step col
    const unsigned aE = (unsigned)labB * 4u;
    const unsigned lbase = (unsigned)(uintptr_t)&plds[0][0][0];
    const unsigned lofs  = (unsigned)l * 16u;

    f32x4v n0, n1;
    {   // prologue: stage rows t=1..16 into buffer 0
        const unsigned voff0 = 1u * 128u + lofs;
        asm volatile("global_load_dwordx4 %0, %1, %2" : "=v"(n0) : "v"(voff0), "s"(xb));
        asm volatile("global_load_dwordx4 %0, %1, %2" : "=v"(n1) : "v"(voff0 + 1024u), "s"(xb));
        asm volatile("s_waitcnt vmcnt(0)" : "+v"(n0), "+v"(n1) :: "memory");
        asm volatile("ds_write_b128 %0, %1" :: "v"(lbase + lofs), "v"(n0) : "memory");
        asm volatile("ds_write_b128 %0, %1" :: "v"(lbase + 1024u + lofs), "v"(n1) : "memory");
    }

    unsigned half = 0;
    int tb = 17;
    for (int g = 0; g < NSTEP / 16; ++g) {
        // issue next group's global loads (overlap the steps)
        const unsigned voffn = (unsigned)tb * 128u + lofs;
        asm volatile("global_load_dwordx4 %0, %1, %2" : "=v"(n0) : "v"(voffn), "s"(xb));
        asm volatile("global_load_dwordx4 %0, %1, %2" : "=v"(n1) : "v"(voffn + 1024u), "s"(xb));
        tb += 16; if (tb > Tn - 17) tb = 1;

        const unsigned hb = lbase + half * 2048u;
        float L0, L1, L2, L3, L4, L5, L6, L7;
        float L8, L9, L10, L11, L12, L13, L14, L15;
#define PDSR(RG, AD) asm volatile("ds_read_b32 %0, %1" : "=v"(RG) : "v"(AD));
        PDSR(L0,  hb +  0u * 128u + aO)  PDSR(L1,  hb +  1u * 128u + aE)
        PDSR(L2,  hb +  2u * 128u + aO)  PDSR(L3,  hb +  3u * 128u + aE)
        PDSR(L4,  hb +  4u * 128u + aO)  PDSR(L5,  hb +  5u * 128u + aE)
        PDSR(L6,  hb +  6u * 128u + aO)  PDSR(L7,  hb +  7u * 128u + aE)
        PDSR(L8,  hb +  8u * 128u + aO)  PDSR(L9,  hb +  9u * 128u + aE)
        PDSR(L10, hb + 10u * 128u + aO)  PDSR(L11, hb + 11u * 128u + aE)
        PDSR(L12, hb + 12u * 128u + aO)  PDSR(L13, hb + 13u * 128u + aE)
        PDSR(L14, hb + 14u * 128u + aO)  PDSR(L15, hb + 15u * 128u + aE)
#undef PDSR
        asm volatile("s_waitcnt lgkmcnt(0)"
            : "+v"(L0), "+v"(L1), "+v"(L2),  "+v"(L3),
              "+v"(L4), "+v"(L5), "+v"(L6),  "+v"(L7),
              "+v"(L8), "+v"(L9), "+v"(L10), "+v"(L11),
              "+v"(L12), "+v"(L13), "+v"(L14), "+v"(L15)
            : : "memory");
        __builtin_amdgcn_sched_barrier(0);

        STEPS16F(L)

        __builtin_amdgcn_sched_barrier(0);
        asm volatile("s_waitcnt vmcnt(0)" : "+v"(n0), "+v"(n1) :: "memory");
        const unsigned wb = lbase + (half ^ 1u) * 2048u;
        asm volatile("ds_write_b128 %0, %1" :: "v"(wb + lofs), "v"(n0) : "memory");
        asm volatile("ds_write_b128 %0, %1" :: "v"(wb + 1024u + lofs), "v"(n1) : "memory");
        half ^= 1u;
    }

    if (l == 0) ws[(size_t)blk * 33] = x + Mr * 1e-30f;
}

// ---- combine kernel: 256 threads (gather latency spread over 4 waves) ------
__global__ __launch_bounds__(256)
void crf_combine_kernel(const float* __restrict__ logits,
                        const float* __restrict__ trans,
                        const int* __restrict__ labels,
                        const int* __restrict__ seq_lens,
                        const float* __restrict__ ws,
                        float* __restrict__ out)
{
    const int b   = blockIdx.x;
    const int tid = threadIdx.x;

    int len = seq_lens[b];
    len = len < 1 ? 1 : (len > Tn ? Tn : len);

    const int*   lb = labels + (size_t)b * Tn;
    const float* xb = logits + (size_t)b * (Tn * Ln);

    float acc = 0.f;
    for (int t = tid; t < len; t += 256) {
        const int lt = lb[t];
        acc += xb[t * Ln + lt];
        if (t >= 1) acc += trans[lb[t - 1] * Ln + lt];
    }
    #pragma unroll
    for (int off = 1; off < 64; off <<= 1)
        acc += __shfl_xor(acc, off);

    __shared__ float wred[4];
    if ((tid & 63) == 0) wred[tid >> 6] = acc;
    __syncthreads();

    if (tid < 64) {
        const float gold = (wred[0] + wred[1]) + (wred[2] + wred[3]);
        const int j = tid & 31;
        const float* wf = ws + (size_t)(b * 2 + 0) * 33;
        const float* wb = ws + (size_t)(b * 2 + 1) * 33;
        float term = wf[j] * wb[j];
        #pragma unroll
        for (int off = 1; off < 32; off <<= 1)
            term += __shfl_xor(term, off);
        if (tid == 0) {
            const float Mf = wf[32], Mb = wb[32];
            out[b] = gold - (Mf + Mb + __builtin_amdgcn_logf(term)) * LN2_F;
        }
    }
}

extern "C" void kernel_launch(void* const* d_in, const int* in_sizes, int n_in,
                              void* d_out, int out_size, void* d_ws, size_t ws_size,
                              hipStream_t stream) {
    const float* logits   = (const float*)d_in[0];
    const float* trans    = (const float*)d_in[1];
    const int*   labels   = (const int*)d_in[2];
    const int*   seq_lens = (const int*)d_in[3];
    float* out = (float*)d_out;
    float* ws  = (float*)d_ws;    // 2048 * 33 floats = 270 KB

    // probe first (speed datum only; ws fully overwritten by chain kernel)
    crf_probe_stage<384><<<Bn * 2, 64, 0, stream>>>(logits, trans, ws);

    crf_chain_kernel<<<Bn * 2, 64, 0, stream>>>(logits, trans, seq_lens, ws);
    crf_combine_kernel<<<Bn, 256, 0, stream>>>(logits, trans, labels, seq_lens, ws, out);
}